// Round 1
// baseline (356.920 us; speedup 1.0000x reference)
//
#include <hip/hip_runtime.h>
#include <hip/hip_bf16.h>

typedef __attribute__((ext_vector_type(8))) short bf16x8;
typedef __attribute__((ext_vector_type(4))) float f32x4;
typedef __attribute__((ext_vector_type(4))) unsigned short u16x4;

#define M_DIM 4096
#define N_DIM 1024
#define IN_F  1024
#define K_DIM 12288   // IN_F * 12  (11 spline slots + 1 residual slot)

__device__ __forceinline__ unsigned short f2b(float v) {
  __hip_bfloat16 h = __float2bfloat16(v);
  return *reinterpret_cast<unsigned short*>(&h);
}

// Uniform cubic B-spline, grid = linspace(-1.75, 1.75, 15), h = 0.25.
// Writes w[0..10] = basis values (only 4 nonzero), w[11] = raw x (residual slot).
__device__ __forceinline__ void spline12(float xv, float* w) {
  float t  = tanhf(xv);
  float tf = (t + 1.75f) * 4.0f;          // in (3,11) since t in (-1,1)
  int j = (int)tf;                         // floor (positive)
  j = j < 3 ? 3 : (j > 10 ? 10 : j);
  float u  = tf - (float)j;               // in [0,1)
  float um = 1.0f - u;
  float u2 = u * u;
  float w0 = um * um * um * (1.0f / 6.0f);
  float w1 = (0.5f * u - 1.0f) * u2 + (2.0f / 3.0f);
  float w2 = ((-0.5f * u + 0.5f) * u + 0.5f) * u + (1.0f / 6.0f);
  float w3 = u * u2 * (1.0f / 6.0f);
  int base = j - 3;                        // in [0,7]
  #pragma unroll
  for (int s = 0; s < 11; ++s) {
    int r = s - base;
    w[s] = (r == 0) ? w0 : (r == 1) ? w1 : (r == 2) ? w2 : (r == 3) ? w3 : 0.0f;
  }
  w[11] = xv;
}

// ---------------- Pass 1b: A[b][i*12+n] bf16 ----------------
__global__ __launch_bounds__(256) void bases_kernel(const float* __restrict__ x,
                                                    unsigned short* __restrict__ A) {
  int idx = blockIdx.x * 256 + threadIdx.x;   // 4096*1024 threads
  float xv = x[idx];
  float w[12];
  spline12(xv, w);
  unsigned short h[12];
  #pragma unroll
  for (int s = 0; s < 12; ++s) h[s] = f2b(w[s]);
  u16x4* dst = (u16x4*)(A + (size_t)idx * 12);   // 24B, 8B-aligned
  dst[0] = (u16x4){h[0], h[1], h[2],  h[3]};
  dst[1] = (u16x4){h[4], h[5], h[6],  h[7]};
  dst[2] = (u16x4){h[8], h[9], h[10], h[11]};
}

// ---------------- Pass 1a: Bt[o][i*12+n] bf16 (transposed repack) ----------------
// grid (16, 64): x -> o-block of 64, y -> i-block of 16
__global__ __launch_bounds__(256) void repack_kernel(const float* __restrict__ coeffs,
                                                     const float* __restrict__ W,
                                                     unsigned short* __restrict__ Bt) {
  __shared__ float lc[16 * 704];   // 16 i x (64 o x 11 n) f32 = 45 KB
  __shared__ float lw[16 * 64];    // base_weight slice
  const int o0 = blockIdx.x * 64;
  const int i0 = blockIdx.y * 16;
  const int tid = threadIdx.x;
  // coalesced f32x4 loads: each i-row is 704 contiguous f32 (16B-aligned)
  for (int v = tid; v < 16 * 176; v += 256) {
    int i = v / 176, c = v - i * 176;
    f32x4 d = *(const f32x4*)(coeffs + ((size_t)(i0 + i) * 1024 + o0) * 11 + c * 4);
    *(f32x4*)(lc + i * 704 + c * 4) = d;
  }
  for (int e = tid; e < 1024; e += 256) {
    int i = e >> 6, o = e & 63;
    lw[e] = W[(size_t)(i0 + i) * 1024 + o0 + o];
  }
  __syncthreads();
  const int o = tid & 63, ig = tid >> 6;
  unsigned short* dst = Bt + (size_t)(o0 + o) * K_DIM + (i0 + ig * 4) * 12;
  #pragma unroll
  for (int ii = 0; ii < 4; ++ii) {
    int i = ig * 4 + ii;
    unsigned short h[12];
    #pragma unroll
    for (int n = 0; n < 11; ++n) h[n] = f2b(lc[i * 704 + o * 11 + n]);
    h[11] = f2b(lw[i * 64 + o]);
    u16x4* d4 = (u16x4*)(dst + ii * 12);
    d4[0] = (u16x4){h[0], h[1], h[2],  h[3]};
    d4[1] = (u16x4){h[4], h[5], h[6],  h[7]};
    d4[2] = (u16x4){h[8], h[9], h[10], h[11]};
  }
}

// ---------------- Pass 2: GEMM C[4096,1024] = A[4096,K] * Bt[1024,K]^T ----------------
__device__ __forceinline__ void async16(const void* g, void* l) {
  __builtin_amdgcn_global_load_lds(
      (const __attribute__((address_space(1))) void*)g,
      (__attribute__((address_space(3))) void*)l, 16, 0, 0);
}

__global__ __launch_bounds__(256, 1) void gemm_kernel(const unsigned short* __restrict__ A,
                                                      const unsigned short* __restrict__ Bt,
                                                      float* __restrict__ out) {
  __shared__ __align__(16) unsigned short As[128 * 64];  // 16 KB, [row][k] xor-swizzled
  __shared__ __align__(16) unsigned short Bs[128 * 64];  // 16 KB, [col][k] xor-swizzled
  const int tid  = threadIdx.x;
  const int lane = tid & 63;
  const int wid  = tid >> 6;
  const int wm   = wid >> 1, wn = wid & 1;

  // XCD-aware mapping: XCD x owns a 4(m) x 8(n) sub-grid (dispatch is round-robin blk%8)
  const int blk = blockIdx.x;
  const int xcd = blk & 7;
  const int r   = blk >> 3;
  const int bm  = xcd * 4 + (r & 3);   // 0..31
  const int bn  = r >> 2;              // 0..7
  const size_t m0 = (size_t)bm * 128;
  const size_t n0 = (size_t)bn * 128;

  // staging: 16 x global_load_lds(16B) per tile per matrix; wave w does q=0..3
  // LDS linear dest; source pre-swizzled: chunk slot s at row rr holds logical chunk s^(rr&7)
  const char* gA[4]; const char* gB[4];
  unsigned short* lA[4]; unsigned short* lB[4];
  #pragma unroll
  for (int q = 0; q < 4; ++q) {
    int rr  = (wid * 4 + q) * 8 + (lane >> 3);
    int c16 = (lane & 7) ^ (rr & 7);
    gA[q] = (const char*)A  + ((m0 + rr) * K_DIM) * 2 + c16 * 16;
    gB[q] = (const char*)Bt + ((n0 + rr) * K_DIM) * 2 + c16 * 16;
    lA[q] = As + (wid * 4 + q) * 512;
    lB[q] = Bs + (wid * 4 + q) * 512;
  }

  // ds_read byte offsets (swizzled), constant over K-loop
  int offA[2][4], offB[2][4];
  #pragma unroll
  for (int kk = 0; kk < 2; ++kk) {
    #pragma unroll
    for (int m = 0; m < 4; ++m) {
      int row = wm * 64 + m * 16 + (lane & 15);
      int ck  = (kk * 4 + (lane >> 4)) ^ (row & 7);
      offA[kk][m] = row * 128 + ck * 16;
      int rowb = wn * 64 + m * 16 + (lane & 15);
      int ckb  = (kk * 4 + (lane >> 4)) ^ (rowb & 7);
      offB[kk][m] = rowb * 128 + ckb * 16;
    }
  }

  f32x4 acc[4][4];
  #pragma unroll
  for (int m = 0; m < 4; ++m)
    #pragma unroll
    for (int n = 0; n < 4; ++n) acc[m][n] = (f32x4){0.f, 0.f, 0.f, 0.f};

  for (int kt = 0; kt < K_DIM / 64; ++kt) {
    const size_t koff = (size_t)kt * 128;   // 64 bf16 = 128 B per K-step
    #pragma unroll
    for (int q = 0; q < 4; ++q) {
      async16(gA[q] + koff, lA[q]);
      async16(gB[q] + koff, lB[q]);
    }
    __syncthreads();   // drains vmcnt -> tile ready
    #pragma unroll
    for (int kk = 0; kk < 2; ++kk) {
      bf16x8 a[4], b[4];
      #pragma unroll
      for (int m = 0; m < 4; ++m)
        a[m] = *(const bf16x8*)((const char*)As + offA[kk][m]);
      #pragma unroll
      for (int n = 0; n < 4; ++n)
        b[n] = *(const bf16x8*)((const char*)Bs + offB[kk][n]);
      #pragma unroll
      for (int m = 0; m < 4; ++m)
        #pragma unroll
        for (int n = 0; n < 4; ++n)
          acc[m][n] = __builtin_amdgcn_mfma_f32_16x16x32_bf16(a[m], b[n], acc[m][n], 0, 0, 0);
    }
    __syncthreads();   // protect LDS before next stage
  }

  const int lr = (lane >> 4) * 4;   // C/D layout: col=lane&15, row=(lane>>4)*4+j
  const int lc = lane & 15;
  #pragma unroll
  for (int m = 0; m < 4; ++m)
    #pragma unroll
    for (int n = 0; n < 4; ++n)
      #pragma unroll
      for (int j = 0; j < 4; ++j)
        out[(m0 + wm * 64 + m * 16 + lr + j) * N_DIM + n0 + wn * 64 + n * 16 + lc] = acc[m][n][j];
}

// ---------------- Fallback (correctness insurance if ws too small) ----------------
// grid (16, 256): x -> o-block of 64, y -> b-block of 16
__global__ __launch_bounds__(256) void fallback_kernel(const float* __restrict__ x,
                                                       const float* __restrict__ coeffs,
                                                       const float* __restrict__ W,
                                                       float* __restrict__ out) {
  __shared__ float bas[16][64][12];   // 48 KB
  const int o0 = blockIdx.x * 64;
  const int b0 = blockIdx.y * 16;
  const int tid = threadIdx.x;
  const int o = tid & 63, bg = tid >> 6;
  float acc[4] = {0.f, 0.f, 0.f, 0.f};
  for (int ic = 0; ic < 16; ++ic) {
    __syncthreads();
    #pragma unroll
    for (int p = 0; p < 4; ++p) {
      int pp = tid + p * 256;
      int bb = pp >> 6, il = pp & 63;
      float w[12];
      spline12(x[(size_t)(b0 + bb) * 1024 + ic * 64 + il], w);
      #pragma unroll
      for (int n = 0; n < 12; ++n) bas[bb][il][n] = w[n];
    }
    __syncthreads();
    for (int il = 0; il < 64; ++il) {
      int gi = ic * 64 + il;
      const float* cp = coeffs + ((size_t)gi * 1024 + o0 + o) * 11;
      float cf[12];
      #pragma unroll
      for (int n = 0; n < 11; ++n) cf[n] = cp[n];
      cf[11] = W[(size_t)gi * 1024 + o0 + o];
      #pragma unroll
      for (int bb = 0; bb < 4; ++bb) {
        float s = 0.f;
        #pragma unroll
        for (int n = 0; n < 12; ++n) s += bas[bg * 4 + bb][il][n] * cf[n];
        acc[bb] += s;
      }
    }
  }
  #pragma unroll
  for (int bb = 0; bb < 4; ++bb)
    out[(size_t)(b0 + bg * 4 + bb) * 1024 + o0 + o] = acc[bb];
}

extern "C" void kernel_launch(void* const* d_in, const int* in_sizes, int n_in,
                              void* d_out, int out_size, void* d_ws, size_t ws_size,
                              hipStream_t stream) {
  const float* x      = (const float*)d_in[0];   // [4096,1024]
  const float* coeffs = (const float*)d_in[1];   // [1024,1024,11]
  const float* W      = (const float*)d_in[2];   // [1024,1024]
  // d_in[3] = grid (uniform, hardcoded)
  float* out = (float*)d_out;

  const size_t needA = (size_t)M_DIM * K_DIM * 2;   // 100,663,296 B
  const size_t needB = (size_t)N_DIM * K_DIM * 2;   //  25,165,824 B

  if (ws_size >= needA + needB) {
    unsigned short* Abuf = (unsigned short*)d_ws;
    unsigned short* Btuf = (unsigned short*)((char*)d_ws + needA);
    bases_kernel<<<dim3(M_DIM * IN_F / 256), dim3(256), 0, stream>>>(x, Abuf);
    repack_kernel<<<dim3(16, 64), dim3(256), 0, stream>>>(coeffs, W, Btuf);
    gemm_kernel<<<dim3(256), dim3(256), 0, stream>>>(Abuf, Btuf, out);
  } else {
    fallback_kernel<<<dim3(16, 256), dim3(256), 0, stream>>>(x, coeffs, W, out);
  }
}

// Round 2
// 272.902 us; speedup vs baseline: 1.3079x; 1.3079x over previous
//
#include <hip/hip_runtime.h>
#include <hip/hip_bf16.h>

typedef __attribute__((ext_vector_type(8))) short bf16x8;
typedef __attribute__((ext_vector_type(4))) float f32x4;
typedef __attribute__((ext_vector_type(4))) unsigned short u16x4;
typedef __attribute__((ext_vector_type(8))) unsigned short u16x8;

#define M_DIM 4096
#define N_DIM 1024
#define IN_F  1024
#define K_DIM 12288   // IN_F * 12  (11 spline slots + 1 residual slot)
#define KSLICE 4
#define KPART (K_DIM / KSLICE)   // 3072

__device__ __forceinline__ unsigned short f2b(float v) {
  __hip_bfloat16 h = __float2bfloat16(v);
  return *reinterpret_cast<unsigned short*>(&h);
}

// Uniform cubic B-spline, grid = linspace(-1.75, 1.75, 15), h = 0.25.
__device__ __forceinline__ void spline12(float xv, float* w) {
  float t  = tanhf(xv);
  float tf = (t + 1.75f) * 4.0f;          // in (3,11) since t in (-1,1)
  int j = (int)tf;
  j = j < 3 ? 3 : (j > 10 ? 10 : j);
  float u  = tf - (float)j;
  float um = 1.0f - u;
  float u2 = u * u;
  float w0 = um * um * um * (1.0f / 6.0f);
  float w1 = (0.5f * u - 1.0f) * u2 + (2.0f / 3.0f);
  float w2 = ((-0.5f * u + 0.5f) * u + 0.5f) * u + (1.0f / 6.0f);
  float w3 = u * u2 * (1.0f / 6.0f);
  int base = j - 3;                        // in [0,7]
  #pragma unroll
  for (int s = 0; s < 11; ++s) {
    int r = s - base;
    w[s] = (r == 0) ? w0 : (r == 1) ? w1 : (r == 2) ? w2 : (r == 3) ? w3 : 0.0f;
  }
  w[11] = xv;
}

// ---------------- Pass 1b: A[b][i*12+n] bf16 ----------------
__global__ __launch_bounds__(256) void bases_kernel(const float* __restrict__ x,
                                                    unsigned short* __restrict__ A) {
  int idx = blockIdx.x * 256 + threadIdx.x;
  float xv = x[idx];
  float w[12];
  spline12(xv, w);
  unsigned short h[12];
  #pragma unroll
  for (int s = 0; s < 12; ++s) h[s] = f2b(w[s]);
  u16x4* dst = (u16x4*)(A + (size_t)idx * 12);
  dst[0] = (u16x4){h[0], h[1], h[2],  h[3]};
  dst[1] = (u16x4){h[4], h[5], h[6],  h[7]};
  dst[2] = (u16x4){h[8], h[9], h[10], h[11]};
}

// ---------------- Pass 1a: Bt[o][i*12+n] bf16 (coalesced transpose) ----------------
// grid (64, 16): block covers o-chunk of 16 (x), i-chunk of 64 (y).
__global__ __launch_bounds__(256) void repack_kernel(const float* __restrict__ coeffs,
                                                     const float* __restrict__ W,
                                                     unsigned short* __restrict__ Bt) {
  __shared__ float lc[64 * 176];   // [i][ol*11+n] f32 = 45 KB
  __shared__ float lw[64 * 16];    // [i][ol] f32 = 4 KB
  const int o0 = blockIdx.x * 16;
  const int i0 = blockIdx.y * 64;
  const int tid = threadIdx.x;
  // load coeffs slice: 64 i x 176 f32 (contiguous per i), 2816 f32x4 loads
  #pragma unroll
  for (int it = 0; it < 11; ++it) {
    int v = it * 256 + tid;            // < 2816
    int i = v / 44, c = v - i * 44;
    f32x4 d = *(const f32x4*)(coeffs + ((size_t)(i0 + i) * 1024 + o0) * 11 + c * 4);
    *(f32x4*)(lc + i * 176 + c * 4) = d;
  }
  #pragma unroll
  for (int it = 0; it < 4; ++it) {
    int e = it * 256 + tid;            // < 1024
    int i = e >> 4, ol = e & 15;
    lw[e] = W[(size_t)(i0 + i) * 1024 + o0 + ol];
  }
  __syncthreads();
  // emit: per o-row, 64 i x 12 u16 = 96 x u16x8 chunks, coalesced along K
  #pragma unroll
  for (int it = 0; it < 6; ++it) {
    int v = it * 256 + tid;            // < 1536
    int ol = v / 96, c = v - ol * 96;
    unsigned short h[8];
    #pragma unroll
    for (int s = 0; s < 8; ++s) {
      int g = c * 8 + s;
      int i = g / 12, n = g - i * 12;
      float val = (n < 11) ? lc[i * 176 + ol * 11 + n] : lw[i * 16 + ol];
      h[s] = f2b(val);
    }
    *(u16x8*)(Bt + (size_t)(o0 + ol) * K_DIM + (size_t)i0 * 12 + c * 8) =
        (u16x8){h[0], h[1], h[2], h[3], h[4], h[5], h[6], h[7]};
  }
}

// ---------------- Pass 2: split-K GEMM, C += A[4096,K] * Bt[1024,K]^T ----------------
__device__ __forceinline__ void async16(const void* g, void* l) {
  __builtin_amdgcn_global_load_lds(
      (const __attribute__((address_space(1))) void*)g,
      (__attribute__((address_space(3))) void*)l, 16, 0, 0);
}

__global__ __launch_bounds__(256, 4) void gemm_kernel(const unsigned short* __restrict__ A,
                                                      const unsigned short* __restrict__ Bt,
                                                      float* __restrict__ out) {
  __shared__ __align__(16) unsigned short As[128 * 64];  // 16 KB, xor-swizzled
  __shared__ __align__(16) unsigned short Bs[128 * 64];  // 16 KB, xor-swizzled
  const int tid  = threadIdx.x;
  const int lane = tid & 63;
  const int wid  = tid >> 6;
  const int wm   = wid >> 1, wn = wid & 1;

  // 1024 blocks: xcd-round-robin low bits; per XCD 4 m-blocks x 8 n x 4 kslices
  const int blk = blockIdx.x;
  const int xcd = blk & 7;
  const int idx = blk >> 3;          // 0..127
  const int ks  = idx & 3;
  const int q   = idx >> 2;          // 0..31
  const int bn  = q & 7;
  const int bm  = xcd * 4 + (q >> 3);
  const size_t m0 = (size_t)bm * 128;
  const size_t n0 = (size_t)bn * 128;
  const size_t kbyte = (size_t)ks * KPART * 2;   // byte offset of this K-slice

  // staging addresses: LDS linear dest; global source pre-swizzled (rule #21)
  const char* gA[4]; const char* gB[4];
  unsigned short* lA[4]; unsigned short* lB[4];
  #pragma unroll
  for (int p = 0; p < 4; ++p) {
    int rr  = (wid * 4 + p) * 8 + (lane >> 3);
    int c16 = (lane & 7) ^ (rr & 7);
    gA[p] = (const char*)A  + ((m0 + rr) * K_DIM) * 2 + kbyte + c16 * 16;
    gB[p] = (const char*)Bt + ((n0 + rr) * K_DIM) * 2 + kbyte + c16 * 16;
    lA[p] = As + (wid * 4 + p) * 512;
    lB[p] = Bs + (wid * 4 + p) * 512;
  }

  int offA[2][4], offB[2][4];
  #pragma unroll
  for (int kk = 0; kk < 2; ++kk) {
    #pragma unroll
    for (int m = 0; m < 4; ++m) {
      int row = wm * 64 + m * 16 + (lane & 15);
      int ck  = (kk * 4 + (lane >> 4)) ^ (row & 7);
      offA[kk][m] = row * 128 + ck * 16;
      int rowb = wn * 64 + m * 16 + (lane & 15);
      int ckb  = (kk * 4 + (lane >> 4)) ^ (rowb & 7);
      offB[kk][m] = rowb * 128 + ckb * 16;
    }
  }

  f32x4 acc[4][4];
  #pragma unroll
  for (int m = 0; m < 4; ++m)
    #pragma unroll
    for (int n = 0; n < 4; ++n) acc[m][n] = (f32x4){0.f, 0.f, 0.f, 0.f};

  for (int kt = 0; kt < KPART / 64; ++kt) {
    const size_t koff = (size_t)kt * 128;
    #pragma unroll
    for (int p = 0; p < 4; ++p) {
      async16(gA[p] + koff, lA[p]);
      async16(gB[p] + koff, lB[p]);
    }
    __syncthreads();
    #pragma unroll
    for (int kk = 0; kk < 2; ++kk) {
      bf16x8 a[4], b[4];
      #pragma unroll
      for (int m = 0; m < 4; ++m)
        a[m] = *(const bf16x8*)((const char*)As + offA[kk][m]);
      #pragma unroll
      for (int n = 0; n < 4; ++n)
        b[n] = *(const bf16x8*)((const char*)Bs + offB[kk][n]);
      #pragma unroll
      for (int m = 0; m < 4; ++m)
        #pragma unroll
        for (int n = 0; n < 4; ++n)
          acc[m][n] = __builtin_amdgcn_mfma_f32_16x16x32_bf16(a[m], b[n], acc[m][n], 0, 0, 0);
    }
    __syncthreads();
  }

  const int lr = (lane >> 4) * 4;   // C/D: col=lane&15, row=(lane>>4)*4+j
  const int lc = lane & 15;
  #pragma unroll
  for (int m = 0; m < 4; ++m)
    #pragma unroll
    for (int n = 0; n < 4; ++n)
      #pragma unroll
      for (int j = 0; j < 4; ++j)
        atomicAdd(&out[(m0 + wm * 64 + m * 16 + lr + j) * N_DIM + n0 + wn * 64 + n * 16 + lc],
                  acc[m][n][j]);
}

// ---------------- Fallback (correctness insurance if ws too small) ----------------
__global__ __launch_bounds__(256) void fallback_kernel(const float* __restrict__ x,
                                                       const float* __restrict__ coeffs,
                                                       const float* __restrict__ W,
                                                       float* __restrict__ out) {
  __shared__ float bas[16][64][12];
  const int o0 = blockIdx.x * 64;
  const int b0 = blockIdx.y * 16;
  const int tid = threadIdx.x;
  const int o = tid & 63, bg = tid >> 6;
  float acc[4] = {0.f, 0.f, 0.f, 0.f};
  for (int ic = 0; ic < 16; ++ic) {
    __syncthreads();
    #pragma unroll
    for (int p = 0; p < 4; ++p) {
      int pp = tid + p * 256;
      int bb = pp >> 6, il = pp & 63;
      float w[12];
      spline12(x[(size_t)(b0 + bb) * 1024 + ic * 64 + il], w);
      #pragma unroll
      for (int n = 0; n < 12; ++n) bas[bb][il][n] = w[n];
    }
    __syncthreads();
    for (int il = 0; il < 64; ++il) {
      int gi = ic * 64 + il;
      const float* cp = coeffs + ((size_t)gi * 1024 + o0 + o) * 11;
      float cf[12];
      #pragma unroll
      for (int n = 0; n < 11; ++n) cf[n] = cp[n];
      cf[11] = W[(size_t)gi * 1024 + o0 + o];
      #pragma unroll
      for (int bb = 0; bb < 4; ++bb) {
        float s = 0.f;
        #pragma unroll
        for (int n = 0; n < 12; ++n) s += bas[bg * 4 + bb][il][n] * cf[n];
        acc[bb] += s;
      }
    }
  }
  #pragma unroll
  for (int bb = 0; bb < 4; ++bb)
    out[(size_t)(b0 + bg * 4 + bb) * 1024 + o0 + o] = acc[bb];
}

extern "C" void kernel_launch(void* const* d_in, const int* in_sizes, int n_in,
                              void* d_out, int out_size, void* d_ws, size_t ws_size,
                              hipStream_t stream) {
  const float* x      = (const float*)d_in[0];   // [4096,1024]
  const float* coeffs = (const float*)d_in[1];   // [1024,1024,11]
  const float* W      = (const float*)d_in[2];   // [1024,1024]
  float* out = (float*)d_out;

  const size_t needA = (size_t)M_DIM * K_DIM * 2;
  const size_t needB = (size_t)N_DIM * K_DIM * 2;

  if (ws_size >= needA + needB) {
    unsigned short* Abuf = (unsigned short*)d_ws;
    unsigned short* Btuf = (unsigned short*)((char*)d_ws + needA);
    hipMemsetAsync(out, 0, (size_t)out_size * sizeof(float), stream);
    bases_kernel<<<dim3(M_DIM * IN_F / 256), dim3(256), 0, stream>>>(x, Abuf);
    repack_kernel<<<dim3(64, 16), dim3(256), 0, stream>>>(coeffs, W, Btuf);
    gemm_kernel<<<dim3(32 * 8 * KSLICE), dim3(256), 0, stream>>>(Abuf, Btuf, out);
  } else {
    fallback_kernel<<<dim3(16, 256), dim3(256), 0, stream>>>(x, coeffs, W, out);
  }
}